// Round 4
// baseline (163.513 us; speedup 1.0000x reference)
//
#include <hip/hip_runtime.h>

// out[b,t,u,v] = ye[b,t,v] + yp[b,u,v]
//   ye = enc@W0@W1 (no biases), yp = (pred@W0 + b0)@W1 + b1.
// Split-K=4 GEMMs write partials:
//   GEMM1: P0..P3 = [enc;pred]@W0, b0 added by z==0 blocks to pred rows.
//   GEMM2: Q0..Q3 = (sum P)@W1,    b1 added by z==0 blocks to pred rows.
//   finalize: yF = Q0+Q1+Q2+Q3 (all 1280 rows).
//   bcast: out[bt,u,v] = yF[bt,v] + yF[1024 + b*128+u, v], nontemporal stores.

#define BM 64
#define BN 64
#define BK 16
#define LDSS 68     // padded LDS row stride (floats)
#define SPLITK 4
#define MROWS 1280

typedef float vf4 __attribute__((ext_vector_type(4)));   // native vector: OK for nontemporal builtins

__device__ __forceinline__ float4 f4add(float4 a, float4 b) {
    a.x += b.x; a.y += b.y; a.z += b.z; a.w += b.w; return a;
}

// MODE 0: A rows from [A0 (1024 rows); A1 (256 rows)] raw (enc;pred).
// MODE 1: A[r][k] = sum_z P[z][r][k], partial stride aStride elements.
template<int MODE>
__global__ __launch_bounds__(256) void gemm_sk(
    const float* __restrict__ A0, const float* __restrict__ A1,
    const float* __restrict__ biasv,     // added at epilogue by z==0 blocks, rows >= 1024
    const float* __restrict__ Bmat,
    float* __restrict__ Cbase,           // partial z at Cbase + z*MROWS*N
    int N, int K, int aStride)
{
    __shared__ float As[2][BK][LDSS];   // transposed: As[.][k][m]
    __shared__ float Bs[2][BK][LDSS];   // Bs[.][k][n]

    const int tid = threadIdx.x;
    const int tx = tid & 15;
    const int ty = tid >> 4;
    const int row0 = blockIdx.y * BM;
    const int col0 = blockIdx.x * BN;
    const int Kchunk = K / SPLITK;
    const int kbeg = blockIdx.z * Kchunk;
    const int kend = kbeg + Kchunk;
    float* __restrict__ C = Cbase + (size_t)blockIdx.z * MROWS * N;

    const int la_row = tid >> 2;        // 0..63
    const int la_k4  = (tid & 3) << 2;  // 0,4,8,12
    const int lb_k   = tid >> 4;        // 0..15
    const int lb_n4  = (tid & 15) << 2; // 0..60

    auto loadA = [&](int k0) -> float4 {
        if (MODE == 0) {
            const float* Ar = (row0 < 1024)
                ? A0 + (size_t)(row0 + la_row) * K
                : A1 + (size_t)(row0 - 1024 + la_row) * K;
            return *reinterpret_cast<const float4*>(Ar + k0 + la_k4);
        } else {
            const size_t o = (size_t)(row0 + la_row) * K + k0 + la_k4;
            float4 a = f4add(*reinterpret_cast<const float4*>(A0 + o),
                             *reinterpret_cast<const float4*>(A0 + aStride + o));
            float4 c = f4add(*reinterpret_cast<const float4*>(A0 + 2 * (size_t)aStride + o),
                             *reinterpret_cast<const float4*>(A0 + 3 * (size_t)aStride + o));
            return f4add(a, c);
        }
    };
    auto loadB = [&](int k0) -> float4 {
        return *reinterpret_cast<const float4*>(
            Bmat + (size_t)(k0 + lb_k) * N + col0 + lb_n4);
    };
    auto stage = [&](int buf, float4 av, float4 bv) {
        As[buf][la_k4 + 0][la_row] = av.x;
        As[buf][la_k4 + 1][la_row] = av.y;
        As[buf][la_k4 + 2][la_row] = av.z;
        As[buf][la_k4 + 3][la_row] = av.w;
        *reinterpret_cast<float4*>(&Bs[buf][lb_k][lb_n4]) = bv;
    };

    float acc[4][4] = {};
    auto compute = [&](int buf) {
        #pragma unroll
        for (int kk = 0; kk < BK; ++kk) {
            float4 a = *reinterpret_cast<const float4*>(&As[buf][kk][ty << 2]);
            float4 b = *reinterpret_cast<const float4*>(&Bs[buf][kk][tx << 2]);
            float af[4] = {a.x, a.y, a.z, a.w};
            float bf[4] = {b.x, b.y, b.z, b.w};
            #pragma unroll
            for (int i = 0; i < 4; ++i)
                #pragma unroll
                for (int j = 0; j < 4; ++j)
                    acc[i][j] = fmaf(af[i], bf[j], acc[i][j]);
        }
    };

    stage(0, loadA(kbeg), loadB(kbeg));
    __syncthreads();
    int buf = 0;
    for (int k0 = kbeg + BK; k0 < kend; k0 += BK) {
        float4 av = loadA(k0);   // prefetch — latency hides under compute
        float4 bv = loadB(k0);
        compute(buf);
        stage(buf ^ 1, av, bv);  // other buffer: safe to write before sync
        __syncthreads();
        buf ^= 1;
    }
    compute(buf);

    const bool doBias = (blockIdx.z == 0) && (row0 >= 1024);
    #pragma unroll
    for (int i = 0; i < 4; ++i) {
        const int r = row0 + (ty << 2) + i;
        const int c = col0 + (tx << 2);
        float4 v = make_float4(acc[i][0], acc[i][1], acc[i][2], acc[i][3]);
        if (doBias) {
            v.x += biasv[c];
            v.y += biasv[c + 1];
            v.z += biasv[c + 2];
            v.w += biasv[c + 3];
        }
        *reinterpret_cast<float4*>(C + (size_t)r * N + c) = v;
    }
}

// yF[i] = Q0[i]+Q1[i]+Q2[i]+Q3[i], i over 1280*256 float4 (partial stride 320K float4)
__global__ __launch_bounds__(256) void finalize_y(
    const float4* __restrict__ Q, float4* __restrict__ yF)
{
    const size_t i = (size_t)blockIdx.x * 256 + threadIdx.x;
    const size_t s = (size_t)MROWS * 256;   // float4 per partial
    yF[i] = f4add(f4add(Q[i], Q[i + s]), f4add(Q[i + 2 * s], Q[i + 3 * s]));
}

// out[(bt*128 + u)*256 + v4] = yeF[bt*256+v4] + ypF[(b*128+u)*256+v4]
// grid 512: bid -> bt0 = (bid>>1)*4 (4 bt rows), uh = bid&1 (64-u half).
__global__ __launch_bounds__(256) void bcast_add(
    const vf4* __restrict__ yF, vf4* __restrict__ out)
{
    const int bid = blockIdx.x;
    const int bt0 = (bid >> 1) << 2;    // 0,4,...,1020
    const int uh = bid & 1;
    const int v4 = threadIdx.x;         // 0..255
    const int b = bt0 >> 9;

    vf4 ye0 = yF[((size_t)(bt0 + 0) << 8) + v4];
    vf4 ye1 = yF[((size_t)(bt0 + 1) << 8) + v4];
    vf4 ye2 = yF[((size_t)(bt0 + 2) << 8) + v4];
    vf4 ye3 = yF[((size_t)(bt0 + 3) << 8) + v4];

    const vf4* yp = yF + ((size_t)(1024 + b * 128 + uh * 64) << 8) + v4;
    vf4* o0 = out + (((size_t)(bt0 + 0) * 128 + uh * 64) << 8) + v4;
    vf4* o1 = out + (((size_t)(bt0 + 1) * 128 + uh * 64) << 8) + v4;
    vf4* o2 = out + (((size_t)(bt0 + 2) * 128 + uh * 64) << 8) + v4;
    vf4* o3 = out + (((size_t)(bt0 + 3) * 128 + uh * 64) << 8) + v4;

    #pragma unroll 4
    for (int u = 0; u < 64; ++u) {
        const size_t off = (size_t)u << 8;
        vf4 p = yp[off];
        __builtin_nontemporal_store(ye0 + p, o0 + off);
        __builtin_nontemporal_store(ye1 + p, o1 + off);
        __builtin_nontemporal_store(ye2 + p, o2 + off);
        __builtin_nontemporal_store(ye3 + p, o3 + off);
    }
}

extern "C" void kernel_launch(void* const* d_in, const int* in_sizes, int n_in,
                              void* d_out, int out_size, void* d_ws, size_t ws_size,
                              hipStream_t stream)
{
    const float* pred = (const float*)d_in[0];  // [2,128,512]
    const float* enc  = (const float*)d_in[1];  // [2,512,512]
    const float* W0   = (const float*)d_in[2];  // [512,512]
    const float* b0   = (const float*)d_in[3];  // [512]
    const float* W1   = (const float*)d_in[4];  // [512,1024]
    const float* b1   = (const float*)d_in[5];  // [1024]
    float* out = (float*)d_out;                 // [2,512,128,1024] fp32

    const int D = 512, H = 512, V = 1024;

    float* P  = (float*)d_ws;                        // 4 x [1280][512]
    float* Q  = P + (size_t)SPLITK * MROWS * H;      // 4 x [1280][1024]
    float* yF = Q + (size_t)SPLITK * MROWS * V;      // [1280][1024]

    // P partials = [enc;pred] @ W0, b0 on pred rows via z==0
    gemm_sk<0><<<dim3(H / BN, MROWS / BM, SPLITK), 256, 0, stream>>>(
        enc, pred, b0, W0, P, H, D, 0);

    // Q partials = (sum P) @ W1, b1 on pred rows via z==0
    gemm_sk<1><<<dim3(V / BN, MROWS / BM, SPLITK), 256, 0, stream>>>(
        P, nullptr, b1, W1, Q, V, H, MROWS * H);

    // yF = sum Q  (rows 0..1023 = ye, 1024..1279 = yp)
    finalize_y<<<MROWS, 256, 0, stream>>>((const float4*)Q, (float4*)yF);

    // out = ye + yp (536 MB nontemporal write)
    bcast_add<<<512, 256, 0, stream>>>((const vf4*)yF, (vf4*)out);
}

// Round 5
// 149.380 us; speedup vs baseline: 1.0946x; 1.0946x over previous
//
#include <hip/hip_runtime.h>

// out[b,t,u,v] = ye[b,t,v] + yp[b,u,v]
//   ye = enc@W0@W1 (no biases), yp = (pred@W0 + b0)@W1 + b1.
// Split-K=4 GEMMs write partials:
//   GEMM1: P0..P3 = [enc;pred]@W0, b0 added by z==0 blocks to pred rows.
//   GEMM2: Q0..Q3 = (sum_z P)@W1,  b1 added by z==0 blocks to pred rows.
//   finalize_yp: ypF = sum_z Q (pred rows only, 1 MB).
//   bcast (R2 structure): out[bt,u,v] = (sum_z Q[z][bt,v]) + ypF[b,u,v].

#define BM 64
#define BN 64
#define BK 16
#define LDSS 68     // padded LDS row stride (floats)
#define SPLITK 4
#define MROWS 1280

__device__ __forceinline__ float4 f4add(float4 a, float4 b) {
    a.x += b.x; a.y += b.y; a.z += b.z; a.w += b.w; return a;
}

// MODE 0: A rows from [A0 (1024 rows); A1 (256 rows)] raw (enc;pred).
// MODE 1: A[r][k] = sum_z P[z][r][k], partial stride aStride elements.
template<int MODE>
__global__ __launch_bounds__(256) void gemm_sk(
    const float* __restrict__ A0, const float* __restrict__ A1,
    const float* __restrict__ biasv,     // added at epilogue by z==0 blocks, rows >= 1024
    const float* __restrict__ Bmat,
    float* __restrict__ Cbase,           // partial z at Cbase + z*MROWS*N
    int N, int K, int aStride)
{
    __shared__ float As[2][BK][LDSS];   // transposed: As[.][k][m]
    __shared__ float Bs[2][BK][LDSS];   // Bs[.][k][n]

    const int tid = threadIdx.x;
    const int tx = tid & 15;
    const int ty = tid >> 4;
    const int row0 = blockIdx.y * BM;
    const int col0 = blockIdx.x * BN;
    const int Kchunk = K / SPLITK;
    const int kbeg = blockIdx.z * Kchunk;
    const int kend = kbeg + Kchunk;
    float* __restrict__ C = Cbase + (size_t)blockIdx.z * MROWS * N;

    const int la_row = tid >> 2;        // 0..63
    const int la_k4  = (tid & 3) << 2;  // 0,4,8,12
    const int lb_k   = tid >> 4;        // 0..15
    const int lb_n4  = (tid & 15) << 2; // 0..60

    auto loadA = [&](int k0) -> float4 {
        if (MODE == 0) {
            const float* Ar = (row0 < 1024)
                ? A0 + (size_t)(row0 + la_row) * K
                : A1 + (size_t)(row0 - 1024 + la_row) * K;
            return *reinterpret_cast<const float4*>(Ar + k0 + la_k4);
        } else {
            const size_t o = (size_t)(row0 + la_row) * K + k0 + la_k4;
            float4 a = f4add(*reinterpret_cast<const float4*>(A0 + o),
                             *reinterpret_cast<const float4*>(A0 + aStride + o));
            float4 c = f4add(*reinterpret_cast<const float4*>(A0 + 2 * (size_t)aStride + o),
                             *reinterpret_cast<const float4*>(A0 + 3 * (size_t)aStride + o));
            return f4add(a, c);
        }
    };
    auto loadB = [&](int k0) -> float4 {
        return *reinterpret_cast<const float4*>(
            Bmat + (size_t)(k0 + lb_k) * N + col0 + lb_n4);
    };
    auto stage = [&](int buf, float4 av, float4 bv) {
        As[buf][la_k4 + 0][la_row] = av.x;
        As[buf][la_k4 + 1][la_row] = av.y;
        As[buf][la_k4 + 2][la_row] = av.z;
        As[buf][la_k4 + 3][la_row] = av.w;
        *reinterpret_cast<float4*>(&Bs[buf][lb_k][lb_n4]) = bv;
    };

    float acc[4][4] = {};
    auto compute = [&](int buf) {
        #pragma unroll
        for (int kk = 0; kk < BK; ++kk) {
            float4 a = *reinterpret_cast<const float4*>(&As[buf][kk][ty << 2]);
            float4 b = *reinterpret_cast<const float4*>(&Bs[buf][kk][tx << 2]);
            float af[4] = {a.x, a.y, a.z, a.w};
            float bf[4] = {b.x, b.y, b.z, b.w};
            #pragma unroll
            for (int i = 0; i < 4; ++i)
                #pragma unroll
                for (int j = 0; j < 4; ++j)
                    acc[i][j] = fmaf(af[i], bf[j], acc[i][j]);
        }
    };

    stage(0, loadA(kbeg), loadB(kbeg));
    __syncthreads();
    int buf = 0;
    for (int k0 = kbeg + BK; k0 < kend; k0 += BK) {
        float4 av = loadA(k0);   // prefetch — latency hides under compute
        float4 bv = loadB(k0);
        compute(buf);
        stage(buf ^ 1, av, bv);  // other buffer: safe to write before sync
        __syncthreads();
        buf ^= 1;
    }
    compute(buf);

    const bool doBias = (blockIdx.z == 0) && (row0 >= 1024);
    #pragma unroll
    for (int i = 0; i < 4; ++i) {
        const int r = row0 + (ty << 2) + i;
        const int c = col0 + (tx << 2);
        float4 v = make_float4(acc[i][0], acc[i][1], acc[i][2], acc[i][3]);
        if (doBias) {
            v.x += biasv[c];
            v.y += biasv[c + 1];
            v.z += biasv[c + 2];
            v.w += biasv[c + 3];
        }
        *reinterpret_cast<float4*>(C + (size_t)r * N + c) = v;
    }
}

// ypF[i] = sum_z Q[z][pred rows], i over 256*256 float4. b1 already in Q (z=0 epilogue).
__global__ __launch_bounds__(256) void finalize_yp(
    const float4* __restrict__ Q, float4* __restrict__ ypF)
{
    const int i = blockIdx.x * 256 + threadIdx.x;   // 0..65535
    const size_t s = (size_t)MROWS * 256;           // float4 per partial
    const size_t o = 262144 + (size_t)i;            // pred rows start (1024*256)
    ypF[i] = f4add(f4add(Q[o], Q[o + s]), f4add(Q[o + 2 * s], Q[o + 3 * s]));
}

// out[(bt*128+u)*256+v4] = (sum_z Q[z][bt*256+v4]) + ypF[(b*128+u)*256+v4]
// grid 2048: bt = bid>>1, uh = bid&1 (64-u half); 256 threads = v4. (R2 structure.)
__global__ __launch_bounds__(256) void bcast_add(
    const float4* __restrict__ Q, const float4* __restrict__ ypF,
    float4* __restrict__ out)
{
    const int bid = blockIdx.x;
    const int bt = bid >> 1;            // 0..1023
    const int uh = bid & 1;
    const int v4 = threadIdx.x;         // 0..255
    const int b = bt >> 9;

    const size_t s = (size_t)MROWS * 256;
    const size_t ybase = ((size_t)bt << 8) + v4;
    float4 ye = f4add(f4add(Q[ybase], Q[ybase + s]),
                      f4add(Q[ybase + 2 * s], Q[ybase + 3 * s]));

    const float4* yp = ypF + ((size_t)(b * 128 + uh * 64) << 8) + v4;
    float4* o = out + (((size_t)bt * 128 + uh * 64) << 8) + v4;
    #pragma unroll 4
    for (int u = 0; u < 64; ++u) {
        o[(size_t)u << 8] = f4add(ye, yp[(size_t)u << 8]);
    }
}

extern "C" void kernel_launch(void* const* d_in, const int* in_sizes, int n_in,
                              void* d_out, int out_size, void* d_ws, size_t ws_size,
                              hipStream_t stream)
{
    const float* pred = (const float*)d_in[0];  // [2,128,512]
    const float* enc  = (const float*)d_in[1];  // [2,512,512]
    const float* W0   = (const float*)d_in[2];  // [512,512]
    const float* b0   = (const float*)d_in[3];  // [512]
    const float* W1   = (const float*)d_in[4];  // [512,1024]
    const float* b1   = (const float*)d_in[5];  // [1024]
    float* out = (float*)d_out;                 // [2,512,128,1024] fp32

    const int D = 512, H = 512, V = 1024;

    float* P   = (float*)d_ws;                       // 4 x [1280][512]
    float* Q   = P + (size_t)SPLITK * MROWS * H;     // 4 x [1280][1024]
    float* ypF = Q + (size_t)SPLITK * MROWS * V;     // [256][1024]

    // P partials = [enc;pred] @ W0, b0 on pred rows via z==0
    gemm_sk<0><<<dim3(H / BN, MROWS / BM, SPLITK), 256, 0, stream>>>(
        enc, pred, b0, W0, P, H, D, 0);

    // Q partials = (sum P) @ W1, b1 on pred rows via z==0
    gemm_sk<1><<<dim3(V / BN, MROWS / BM, SPLITK), 256, 0, stream>>>(
        P, nullptr, b1, W1, Q, V, H, MROWS * H);

    // ypF = sum_z Q (pred rows, 1 MB)
    finalize_yp<<<256, 256, 0, stream>>>((const float4*)Q, (float4*)ypF);

    // out = ye + yp (536 MB write)
    bcast_add<<<2048, 256, 0, stream>>>(
        (const float4*)Q, (const float4*)ypF, (float4*)out);
}

// Round 6
// 148.932 us; speedup vs baseline: 1.0979x; 1.0030x over previous
//
#include <hip/hip_runtime.h>

// out[b,t,u,v] = ye[b,t,v] + yp[b,u,v]
//   ye = enc@W0@W1 (no biases), yp = (pred@W0 + b0)@W1 + b1.
// Split-K=4 GEMMs write partials:
//   GEMM1: P0..P3 = [enc;pred]@W0, b0 added by z==0 blocks to pred rows.
//   GEMM2: Q0..Q3 = (sum_z P)@W1,  b1 added by z==0 blocks to pred rows.
//   finalize_yp: ypF = sum_z Q (pred rows only, 1 MB).
//   bcast (R2 structure + NONTEMPORAL stores): out = ye + yp.

#define BM 64
#define BN 64
#define BK 16
#define LDSS 68     // padded LDS row stride (floats)
#define SPLITK 4
#define MROWS 1280

typedef float vf4 __attribute__((ext_vector_type(4)));   // native vector for nontemporal builtins

__device__ __forceinline__ float4 f4add(float4 a, float4 b) {
    a.x += b.x; a.y += b.y; a.z += b.z; a.w += b.w; return a;
}

// MODE 0: A rows from [A0 (1024 rows); A1 (256 rows)] raw (enc;pred).
// MODE 1: A[r][k] = sum_z P[z][r][k], partial stride aStride elements.
template<int MODE>
__global__ __launch_bounds__(256) void gemm_sk(
    const float* __restrict__ A0, const float* __restrict__ A1,
    const float* __restrict__ biasv,     // added at epilogue by z==0 blocks, rows >= 1024
    const float* __restrict__ Bmat,
    float* __restrict__ Cbase,           // partial z at Cbase + z*MROWS*N
    int N, int K, int aStride)
{
    __shared__ float As[2][BK][LDSS];   // transposed: As[.][k][m]
    __shared__ float Bs[2][BK][LDSS];   // Bs[.][k][n]

    const int tid = threadIdx.x;
    const int tx = tid & 15;
    const int ty = tid >> 4;
    const int row0 = blockIdx.y * BM;
    const int col0 = blockIdx.x * BN;
    const int Kchunk = K / SPLITK;
    const int kbeg = blockIdx.z * Kchunk;
    const int kend = kbeg + Kchunk;
    float* __restrict__ C = Cbase + (size_t)blockIdx.z * MROWS * N;

    const int la_row = tid >> 2;        // 0..63
    const int la_k4  = (tid & 3) << 2;  // 0,4,8,12
    const int lb_k   = tid >> 4;        // 0..15
    const int lb_n4  = (tid & 15) << 2; // 0..60

    auto loadA = [&](int k0) -> float4 {
        if (MODE == 0) {
            const float* Ar = (row0 < 1024)
                ? A0 + (size_t)(row0 + la_row) * K
                : A1 + (size_t)(row0 - 1024 + la_row) * K;
            return *reinterpret_cast<const float4*>(Ar + k0 + la_k4);
        } else {
            const size_t o = (size_t)(row0 + la_row) * K + k0 + la_k4;
            float4 a = f4add(*reinterpret_cast<const float4*>(A0 + o),
                             *reinterpret_cast<const float4*>(A0 + aStride + o));
            float4 c = f4add(*reinterpret_cast<const float4*>(A0 + 2 * (size_t)aStride + o),
                             *reinterpret_cast<const float4*>(A0 + 3 * (size_t)aStride + o));
            return f4add(a, c);
        }
    };
    auto loadB = [&](int k0) -> float4 {
        return *reinterpret_cast<const float4*>(
            Bmat + (size_t)(k0 + lb_k) * N + col0 + lb_n4);
    };
    auto stage = [&](int buf, float4 av, float4 bv) {
        As[buf][la_k4 + 0][la_row] = av.x;
        As[buf][la_k4 + 1][la_row] = av.y;
        As[buf][la_k4 + 2][la_row] = av.z;
        As[buf][la_k4 + 3][la_row] = av.w;
        *reinterpret_cast<float4*>(&Bs[buf][lb_k][lb_n4]) = bv;
    };

    float acc[4][4] = {};
    auto compute = [&](int buf) {
        #pragma unroll
        for (int kk = 0; kk < BK; ++kk) {
            float4 a = *reinterpret_cast<const float4*>(&As[buf][kk][ty << 2]);
            float4 b = *reinterpret_cast<const float4*>(&Bs[buf][kk][tx << 2]);
            float af[4] = {a.x, a.y, a.z, a.w};
            float bf[4] = {b.x, b.y, b.z, b.w};
            #pragma unroll
            for (int i = 0; i < 4; ++i)
                #pragma unroll
                for (int j = 0; j < 4; ++j)
                    acc[i][j] = fmaf(af[i], bf[j], acc[i][j]);
        }
    };

    stage(0, loadA(kbeg), loadB(kbeg));
    __syncthreads();
    int buf = 0;
    for (int k0 = kbeg + BK; k0 < kend; k0 += BK) {
        float4 av = loadA(k0);   // prefetch — latency hides under compute
        float4 bv = loadB(k0);
        compute(buf);
        stage(buf ^ 1, av, bv);  // other buffer: safe to write before sync
        __syncthreads();
        buf ^= 1;
    }
    compute(buf);

    const bool doBias = (blockIdx.z == 0) && (row0 >= 1024);
    #pragma unroll
    for (int i = 0; i < 4; ++i) {
        const int r = row0 + (ty << 2) + i;
        const int c = col0 + (tx << 2);
        float4 v = make_float4(acc[i][0], acc[i][1], acc[i][2], acc[i][3]);
        if (doBias) {
            v.x += biasv[c];
            v.y += biasv[c + 1];
            v.z += biasv[c + 2];
            v.w += biasv[c + 3];
        }
        *reinterpret_cast<float4*>(C + (size_t)r * N + c) = v;
    }
}

// ypF[i] = sum_z Q[z][pred rows], i over 256*256 float4. b1 already in Q (z=0 epilogue).
__global__ __launch_bounds__(256) void finalize_yp(
    const float4* __restrict__ Q, float4* __restrict__ ypF)
{
    const int i = blockIdx.x * 256 + threadIdx.x;   // 0..65535
    const size_t s = (size_t)MROWS * 256;           // float4 per partial
    const size_t o = 262144 + (size_t)i;            // pred rows start (1024*256)
    ypF[i] = f4add(f4add(Q[o], Q[o + s]), f4add(Q[o + 2 * s], Q[o + 3 * s]));
}

// out[(bt*128+u)*256+v4] = (sum_z Q[z][bt*256+v4]) + ypF[(b*128+u)*256+v4]
// grid 2048: bt = bid>>1, uh = bid&1 (64-u half); 256 threads = v4.
// Identical to R5 except stores are nontemporal (bypass L2 for the 536 MB stream).
__global__ __launch_bounds__(256) void bcast_add(
    const vf4* __restrict__ Q, const vf4* __restrict__ ypF,
    vf4* __restrict__ out)
{
    const int bid = blockIdx.x;
    const int bt = bid >> 1;            // 0..1023
    const int uh = bid & 1;
    const int v4 = threadIdx.x;         // 0..255
    const int b = bt >> 9;

    const size_t s = (size_t)MROWS * 256;
    const size_t ybase = ((size_t)bt << 8) + v4;
    vf4 ye = (Q[ybase] + Q[ybase + s]) + (Q[ybase + 2 * s] + Q[ybase + 3 * s]);

    const vf4* yp = ypF + ((size_t)(b * 128 + uh * 64) << 8) + v4;
    vf4* o = out + (((size_t)bt * 128 + uh * 64) << 8) + v4;
    #pragma unroll 4
    for (int u = 0; u < 64; ++u) {
        __builtin_nontemporal_store(ye + yp[(size_t)u << 8], o + ((size_t)u << 8));
    }
}

extern "C" void kernel_launch(void* const* d_in, const int* in_sizes, int n_in,
                              void* d_out, int out_size, void* d_ws, size_t ws_size,
                              hipStream_t stream)
{
    const float* pred = (const float*)d_in[0];  // [2,128,512]
    const float* enc  = (const float*)d_in[1];  // [2,512,512]
    const float* W0   = (const float*)d_in[2];  // [512,512]
    const float* b0   = (const float*)d_in[3];  // [512]
    const float* W1   = (const float*)d_in[4];  // [512,1024]
    const float* b1   = (const float*)d_in[5];  // [1024]
    float* out = (float*)d_out;                 // [2,512,128,1024] fp32

    const int D = 512, H = 512, V = 1024;

    float* P   = (float*)d_ws;                       // 4 x [1280][512]
    float* Q   = P + (size_t)SPLITK * MROWS * H;     // 4 x [1280][1024]
    float* ypF = Q + (size_t)SPLITK * MROWS * V;     // [256][1024]

    // P partials = [enc;pred] @ W0, b0 on pred rows via z==0
    gemm_sk<0><<<dim3(H / BN, MROWS / BM, SPLITK), 256, 0, stream>>>(
        enc, pred, b0, W0, P, H, D, 0);

    // Q partials = (sum P) @ W1, b1 on pred rows via z==0
    gemm_sk<1><<<dim3(V / BN, MROWS / BM, SPLITK), 256, 0, stream>>>(
        P, nullptr, b1, W1, Q, V, H, MROWS * H);

    // ypF = sum_z Q (pred rows, 1 MB)
    finalize_yp<<<256, 256, 0, stream>>>((const float4*)Q, (float4*)ypF);

    // out = ye + yp (536 MB nontemporal write)
    bcast_add<<<2048, 256, 0, stream>>>(
        (const vf4*)Q, (const vf4*)ypF, (vf4*)out);
}